// Round 1
// baseline (250.009 us; speedup 1.0000x reference)
//
#include <hip/hip_runtime.h>
#include <hip/hip_bf16.h>

typedef __attribute__((ext_vector_type(8))) short short8;
typedef __attribute__((ext_vector_type(4))) float float4v;

#define S_DIM 128
#define N_DIM 256
#define CM    256
#define CH    32
#define CZ    128

// ---------------------------------------------------------------------------
// Kernel 1: LayerNorm + dual projection, writes a_t/b_t transposed [N*CH][S] bf16
// Block = 256 thr (4 waves), handles 32 rows (r = s*N + n). ln staged in LDS,
// projection done with 16x16x32 bf16 MFMA against w staged transposed in LDS.
// ---------------------------------------------------------------------------
__global__ __launch_bounds__(256) void prep_kernel(
    const float* __restrict__ m, const float* __restrict__ mask,
    const float* __restrict__ lnw, const float* __restrict__ lnb,
    const float* __restrict__ w1, const float* __restrict__ b1,
    const float* __restrict__ w2, const float* __restrict__ b2,
    __hip_bfloat16* __restrict__ a_t, __hip_bfloat16* __restrict__ b_t)
{
    __shared__ __hip_bfloat16 w_lds[64 * 264];   // w_t[c][k]: c<32 -> w1, c>=32 -> w2, pad 8
    __shared__ __hip_bfloat16 ln_lds[32 * 264];  // ln[row_local][k]

    const int t    = threadIdx.x;
    const int lane = t & 63;
    const int wv   = t >> 6;

    // stage w transposed: w_t[c][k] = w{1,2}[k][c]
    #pragma unroll 4
    for (int i = 0; i < 64; ++i) {
        int e = i * 256 + t;           // 16384 elements
        int k = e >> 6, c = e & 63;
        float v = (c < CH) ? w1[k * CH + c] : w2[k * CH + (c - CH)];
        w_lds[c * 264 + k] = __float2bfloat16(v);
    }

    const int R0 = blockIdx.x * 32;
    float4 lw = ((const float4*)lnw)[lane];
    float4 lb = ((const float4*)lnb)[lane];

    // LayerNorm: each wave does 8 rows
    for (int it = 0; it < 8; ++it) {
        int rl = wv * 8 + it;
        int r  = R0 + rl;
        float4 mv = ((const float4*)(m + (size_t)r * CM))[lane];
        float s1 = mv.x + mv.y + mv.z + mv.w;
        float s2 = mv.x*mv.x + mv.y*mv.y + mv.z*mv.z + mv.w*mv.w;
        #pragma unroll
        for (int o = 32; o > 0; o >>= 1) {
            s1 += __shfl_xor(s1, o, 64);
            s2 += __shfl_xor(s2, o, 64);
        }
        float mu  = s1 * (1.0f / 256.0f);
        float var = s2 * (1.0f / 256.0f) - mu * mu;
        float rs  = rsqrtf(var + 1e-5f);
        int base = rl * 264 + lane * 4;
        ln_lds[base + 0] = __float2bfloat16((mv.x - mu) * rs * lw.x + lb.x);
        ln_lds[base + 1] = __float2bfloat16((mv.y - mu) * rs * lw.y + lb.y);
        ln_lds[base + 2] = __float2bfloat16((mv.z - mu) * rs * lw.z + lb.z);
        ln_lds[base + 3] = __float2bfloat16((mv.w - mu) * rs * lw.w + lb.w);
    }
    __syncthreads();

    // MFMA: [32 rows x 64 cols], wave -> (row-tile rt, col-tiles ctb, ctb+1)
    const int q = lane >> 4, c16 = lane & 15;
    const int rt = wv & 1, ctb = (wv >> 1) * 2;
    float4v acc0 = {0.f, 0.f, 0.f, 0.f};
    float4v acc1 = {0.f, 0.f, 0.f, 0.f};
    #pragma unroll
    for (int ks = 0; ks < 8; ++ks) {
        int k0 = ks * 32 + q * 8;
        short8 af  = *(const short8*)&ln_lds[(rt  * 16      + c16) * 264 + k0];
        short8 wb0 = *(const short8*)&w_lds [( ctb      * 16 + c16) * 264 + k0];
        short8 wb1 = *(const short8*)&w_lds [((ctb + 1) * 16 + c16) * 264 + k0];
        acc0 = __builtin_amdgcn_mfma_f32_16x16x32_bf16(af, wb0, acc0, 0, 0, 0);
        acc1 = __builtin_amdgcn_mfma_f32_16x16x32_bf16(af, wb1, acc1, 0, 0, 0);
    }

    // C/D layout: col = lane&15, row = quad*4 + reg
    #pragma unroll
    for (int tile = 0; tile < 2; ++tile) {
        float4v acc = tile ? acc1 : acc0;
        int cc = (ctb + tile) * 16 + c16;     // 0..63
        #pragma unroll
        for (int rr = 0; rr < 4; ++rr) {
            int rl = rt * 16 + q * 4 + rr;
            int r  = R0 + rl;
            int s  = r >> 8, n = r & 255;     // r = s*256 + n
            float bias = (cc < CH) ? b1[cc] : b2[cc - CH];
            float val  = (acc[rr] + bias) * mask[r];
            __hip_bfloat16 bv = __float2bfloat16(val);
            if (cc < CH) a_t[((size_t)(n * CH + cc)      ) * S_DIM + s] = bv;
            else         b_t[((size_t)(n * CH + cc - CH)) * S_DIM + s] = bv;
        }
    }
}

// ---------------------------------------------------------------------------
// Kernel 2: ninv[i][j] = 1 / (sum_s mask[s,i]*mask[s,j] + 1e-3)
// ---------------------------------------------------------------------------
__global__ __launch_bounds__(256) void norm_kernel(
    const float* __restrict__ mask, float* __restrict__ ninv)
{
    int i = blockIdx.x, j = threadIdx.x;
    float acc = 0.f;
    for (int s = 0; s < S_DIM; ++s)
        acc += mask[s * N_DIM + i] * mask[s * N_DIM + j];
    ninv[i * N_DIM + j] = 1.0f / (acc + 1e-3f);
}

// ---------------------------------------------------------------------------
// Kernel 3: wo_t[z][k] = bf16(wo[k][z]),  [128][1024]
// ---------------------------------------------------------------------------
__global__ __launch_bounds__(256) void wot_kernel(
    const float* __restrict__ wo, __hip_bfloat16* __restrict__ wo_t)
{
    int idx = blockIdx.x * 256 + threadIdx.x;   // 131072
    int z = idx >> 10, kk = idx & 1023;
    wo_t[idx] = __float2bfloat16(wo[kk * CZ + z]);
}

// ---------------------------------------------------------------------------
// Kernel 4: fused outer-product GEMM (8192x8192x128 in 128x128 tiles) +
// per-tile epilogue GEMM [16 pairs x 1024] @ wo_t -> out[4i x 4j x 128]
// ---------------------------------------------------------------------------
__global__ __launch_bounds__(256) void main_kernel(
    const __hip_bfloat16* __restrict__ a_t, const __hip_bfloat16* __restrict__ b_t,
    const __hip_bfloat16* __restrict__ wo_t, const float* __restrict__ bo,
    const float* __restrict__ ninv, float* __restrict__ out)
{
    // LDS overlay: main loop uses A[128][72] + B[128][72] bf16 (36864 B);
    // epilogue overlays P[16][1032] bf16 (33024 B)
    __shared__ ulong2 lds_raw[36864 / 16];
    __hip_bfloat16* Al = (__hip_bfloat16*)lds_raw;
    __hip_bfloat16* Bl = Al + 128 * 72;
    __hip_bfloat16* Pl = (__hip_bfloat16*)lds_raw;

    const int t = threadIdx.x, lane = t & 63, wv = t >> 6;
    const int q = lane >> 4, c16 = lane & 15;
    const int bi = blockIdx.x, bj = blockIdx.y;
    const int wr = wv >> 1, wc = wv & 1;
    const size_t Ibase = (size_t)bi * 128, Jbase = (size_t)bj * 128;

    float4v acc[4][4];
    #pragma unroll
    for (int ti = 0; ti < 4; ++ti)
        #pragma unroll
        for (int tj = 0; tj < 4; ++tj)
            acc[ti][tj] = (float4v){0.f, 0.f, 0.f, 0.f};

    // K = S = 128, staged in 2 halves of 64
    for (int st = 0; st < 2; ++st) {
        if (st) __syncthreads();
        #pragma unroll
        for (int i = 0; i < 4; ++i) {
            int flat = i * 256 + t;          // 1024 ushort8 per array
            int row = flat >> 3, ch = flat & 7;
            *(short8*)&Al[row * 72 + ch * 8] =
                *(const short8*)&a_t[(Ibase + row) * S_DIM + st * 64 + ch * 8];
            *(short8*)&Bl[row * 72 + ch * 8] =
                *(const short8*)&b_t[(Jbase + row) * S_DIM + st * 64 + ch * 8];
        }
        __syncthreads();
        #pragma unroll
        for (int kk = 0; kk < 2; ++kk) {
            int k0 = kk * 32 + q * 8;
            short8 af[4], bf[4];
            #pragma unroll
            for (int ti = 0; ti < 4; ++ti)
                af[ti] = *(const short8*)&Al[(wr * 64 + ti * 16 + c16) * 72 + k0];
            #pragma unroll
            for (int tj = 0; tj < 4; ++tj)
                bf[tj] = *(const short8*)&Bl[(wc * 64 + tj * 16 + c16) * 72 + k0];
            #pragma unroll
            for (int ti = 0; ti < 4; ++ti)
                #pragma unroll
                for (int tj = 0; tj < 4; ++tj)
                    acc[ti][tj] = __builtin_amdgcn_mfma_f32_16x16x32_bf16(
                        af[ti], bf[tj], acc[ti][tj], 0, 0, 0);
        }
    }

    __syncthreads();
    // scatter acc -> P[pair][c*32+d] bf16 (pair = (I>>5)*4 + (J>>5))
    #pragma unroll
    for (int ti = 0; ti < 4; ++ti)
        #pragma unroll
        for (int tj = 0; tj < 4; ++tj)
            #pragma unroll
            for (int rr = 0; rr < 4; ++rr) {
                int Il = wr * 64 + ti * 16 + q * 4 + rr;
                int Jl = wc * 64 + tj * 16 + c16;
                int p  = (Il >> 5) * 4 + (Jl >> 5);
                int kk = (Il & 31) * 32 + (Jl & 31);
                Pl[p * 1032 + kk] = __float2bfloat16(acc[ti][tj][rr]);
            }
    __syncthreads();

    // epilogue GEMM: [16 pairs x 1024] @ wo_t^T -> [16 x 128]; wave wv owns z in [wv*32, wv*32+32)
    float4v oacc0 = {0.f, 0.f, 0.f, 0.f};
    float4v oacc1 = {0.f, 0.f, 0.f, 0.f};
    #pragma unroll 4
    for (int ks = 0; ks < 32; ++ks) {
        int k0 = ks * 32 + q * 8;
        short8 pf  = *(const short8*)&Pl[c16 * 1032 + k0];
        short8 wf0 = *(const short8*)&wo_t[(size_t)(wv * 32      + c16) * 1024 + k0];
        short8 wf1 = *(const short8*)&wo_t[(size_t)(wv * 32 + 16 + c16) * 1024 + k0];
        oacc0 = __builtin_amdgcn_mfma_f32_16x16x32_bf16(pf, wf0, oacc0, 0, 0, 0);
        oacc1 = __builtin_amdgcn_mfma_f32_16x16x32_bf16(pf, wf1, oacc1, 0, 0, 0);
    }

    // C/D: row = pair = q*4+rr -> (i = q, j = rr); col = z offset = c16
    const int gi = bi * 4 + q;
    float nvv[4];
    #pragma unroll
    for (int rr = 0; rr < 4; ++rr)
        nvv[rr] = ninv[gi * N_DIM + bj * 4 + rr];
    #pragma unroll
    for (int tile = 0; tile < 2; ++tile) {
        int z = wv * 32 + tile * 16 + c16;
        float bz = bo[z];
        float4v oacc = tile ? oacc1 : oacc0;
        #pragma unroll
        for (int rr = 0; rr < 4; ++rr) {
            int gj = bj * 4 + rr;
            out[((size_t)gi * N_DIM + gj) * CZ + z] = (oacc[rr] + bz) * nvv[rr];
        }
    }
}

extern "C" void kernel_launch(void* const* d_in, const int* in_sizes, int n_in,
                              void* d_out, int out_size, void* d_ws, size_t ws_size,
                              hipStream_t stream) {
    const float* m    = (const float*)d_in[0];
    const float* mask = (const float*)d_in[1];
    const float* lnw  = (const float*)d_in[2];
    const float* lnb  = (const float*)d_in[3];
    const float* w1   = (const float*)d_in[4];
    const float* b1   = (const float*)d_in[5];
    const float* w2   = (const float*)d_in[6];
    const float* b2   = (const float*)d_in[7];
    const float* wo   = (const float*)d_in[8];
    const float* bo   = (const float*)d_in[9];
    float* out = (float*)d_out;

    char* ws = (char*)d_ws;
    __hip_bfloat16* a_t  = (__hip_bfloat16*)ws;                          // 2 MB
    __hip_bfloat16* b_t  = (__hip_bfloat16*)(ws + (2u << 20));           // 2 MB
    __hip_bfloat16* wo_t = (__hip_bfloat16*)(ws + (4u << 20));           // 256 KB
    float*          ninv = (float*)(ws + (4u << 20) + (256u << 10));     // 256 KB

    prep_kernel<<<1024, 256, 0, stream>>>(m, mask, lnw, lnb, w1, b1, w2, b2, a_t, b_t);
    norm_kernel<<<N_DIM, 256, 0, stream>>>(mask, ninv);
    wot_kernel<<<512, 256, 0, stream>>>(wo, wo_t);
    main_kernel<<<dim3(64, 64), 256, 0, stream>>>(a_t, b_t, wo_t, bo, ninv, out);
}

// Round 3
// 197.001 us; speedup vs baseline: 1.2691x; 1.2691x over previous
//
#include <hip/hip_runtime.h>
#include <hip/hip_bf16.h>

typedef __attribute__((ext_vector_type(8))) short short8;
typedef __attribute__((ext_vector_type(4))) short short4v;
typedef __attribute__((ext_vector_type(4))) float float4v;

#define S_DIM 128
#define N_DIM 256
#define CM    256
#define CH    32
#define CZ    128

static __device__ __forceinline__ short f2bf(float v) {
    return __builtin_bit_cast(short, __float2bfloat16(v));
}

// ---------------------------------------------------------------------------
// Kernel 1: LayerNorm + dual projection -> a_t/b_t transposed [N*CH][S] bf16
// 128 rows (r = s*N + n) per block in 4 batches of 32; w staged once.
// ---------------------------------------------------------------------------
__global__ __launch_bounds__(256) void prep_kernel(
    const float* __restrict__ m, const float* __restrict__ mask,
    const float* __restrict__ lnw, const float* __restrict__ lnb,
    const float* __restrict__ w1, const float* __restrict__ b1,
    const float* __restrict__ w2, const float* __restrict__ b2,
    __hip_bfloat16* __restrict__ a_t, __hip_bfloat16* __restrict__ b_t)
{
    __shared__ __hip_bfloat16 w_lds[64 * 264];   // w_t[c][k], pad 8
    __shared__ __hip_bfloat16 ln_lds[32 * 264];  // ln[row_local][k]

    const int t    = threadIdx.x;
    const int lane = t & 63;
    const int wv   = t >> 6;

    // stage w transposed: w_t[c][k] = w{1,2}[k][c]  (once per 128 rows)
    #pragma unroll 4
    for (int i = 0; i < 64; ++i) {
        int e = i * 256 + t;
        int k = e >> 6, c = e & 63;
        float v = (c < CH) ? w1[k * CH + c] : w2[k * CH + (c - CH)];
        w_lds[c * 264 + k] = __float2bfloat16(v);
    }

    float4 lw = ((const float4*)lnw)[lane];
    float4 lb = ((const float4*)lnb)[lane];
    const int q = lane >> 4, c16 = lane & 15;
    const int rt = wv & 1, ctb = (wv >> 1) * 2;

    for (int bb = 0; bb < 4; ++bb) {
        __syncthreads();   // w ready / previous batch consumed
        const int R0 = blockIdx.x * 128 + bb * 32;

        // LayerNorm: each wave does 8 rows
        for (int it = 0; it < 8; ++it) {
            int rl = wv * 8 + it;
            int r  = R0 + rl;
            float4 mv = ((const float4*)(m + (size_t)r * CM))[lane];
            float s1 = mv.x + mv.y + mv.z + mv.w;
            float s2 = mv.x*mv.x + mv.y*mv.y + mv.z*mv.z + mv.w*mv.w;
            #pragma unroll
            for (int o = 32; o > 0; o >>= 1) {
                s1 += __shfl_xor(s1, o, 64);
                s2 += __shfl_xor(s2, o, 64);
            }
            float mu  = s1 * (1.0f / 256.0f);
            float var = s2 * (1.0f / 256.0f) - mu * mu;
            float rs  = rsqrtf(var + 1e-5f);
            int base = rl * 264 + lane * 4;
            ln_lds[base + 0] = __float2bfloat16((mv.x - mu) * rs * lw.x + lb.x);
            ln_lds[base + 1] = __float2bfloat16((mv.y - mu) * rs * lw.y + lb.y);
            ln_lds[base + 2] = __float2bfloat16((mv.z - mu) * rs * lw.z + lb.z);
            ln_lds[base + 3] = __float2bfloat16((mv.w - mu) * rs * lw.w + lb.w);
        }
        __syncthreads();

        // MFMA: [32 rows x 64 cols]
        float4v acc0 = {0.f, 0.f, 0.f, 0.f};
        float4v acc1 = {0.f, 0.f, 0.f, 0.f};
        #pragma unroll
        for (int ks = 0; ks < 8; ++ks) {
            int k0 = ks * 32 + q * 8;
            short8 af  = *(const short8*)&ln_lds[(rt  * 16      + c16) * 264 + k0];
            short8 wb0 = *(const short8*)&w_lds [( ctb      * 16 + c16) * 264 + k0];
            short8 wb1 = *(const short8*)&w_lds [((ctb + 1) * 16 + c16) * 264 + k0];
            acc0 = __builtin_amdgcn_mfma_f32_16x16x32_bf16(af, wb0, acc0, 0, 0, 0);
            acc1 = __builtin_amdgcn_mfma_f32_16x16x32_bf16(af, wb1, acc1, 0, 0, 0);
        }

        #pragma unroll
        for (int tile = 0; tile < 2; ++tile) {
            float4v acc = tile ? acc1 : acc0;
            int cc = (ctb + tile) * 16 + c16;
            #pragma unroll
            for (int rr = 0; rr < 4; ++rr) {
                int rl = rt * 16 + q * 4 + rr;
                int r  = R0 + rl;
                int s  = r >> 8, n = r & 255;
                float bias = (cc < CH) ? b1[cc] : b2[cc - CH];
                float val  = (acc[rr] + bias) * mask[r];
                __hip_bfloat16 bv = __float2bfloat16(val);
                if (cc < CH) a_t[((size_t)(n * CH + cc)      ) * S_DIM + s] = bv;
                else         b_t[((size_t)(n * CH + cc - CH)) * S_DIM + s] = bv;
            }
        }
    }
}

// ---------------------------------------------------------------------------
// Kernel 2: ninv[i][j] = 1 / (sum_s mask[s,i]*mask[s,j] + 1e-3)
// ---------------------------------------------------------------------------
__global__ __launch_bounds__(256) void norm_kernel(
    const float* __restrict__ mask, float* __restrict__ ninv)
{
    int i = blockIdx.x, j = threadIdx.x;
    float acc = 0.f;
    for (int s = 0; s < S_DIM; ++s)
        acc += mask[s * N_DIM + i] * mask[s * N_DIM + j];
    ninv[i * N_DIM + j] = 1.0f / (acc + 1e-3f);
}

// ---------------------------------------------------------------------------
// Kernel 3: wo -> fragment-ordered wo_f.
// Epilogue k-index permuted: k'' = d*32 + c  <->  k_orig = c*32 + d.
// wo_f[((zt*32 + d)*64 + l)*8 + j] = bf16(wo[((l>>4)*8+j)*32 + d][zt*16 + (l&15)])
// ---------------------------------------------------------------------------
__global__ __launch_bounds__(256) void wot_kernel(
    const float* __restrict__ wo, __hip_bfloat16* __restrict__ wo_f)
{
    int fidx = blockIdx.x * 256 + threadIdx.x;   // 16384 lane-slots
    int l  = fidx & 63;
    int d  = (fidx >> 6) & 31;
    int zt = fidx >> 11;
    int z  = zt * 16 + (l & 15);
    int cb = (l >> 4) * 8;
    short8 frag;
    #pragma unroll
    for (int j = 0; j < 8; ++j) {
        float v = wo[(size_t)((cb + j) * 32 + d) * CZ + z];
        frag[j] = f2bf(v);
    }
    *(short8*)&wo_f[(size_t)fidx * 8] = frag;
}

// ---------------------------------------------------------------------------
// Kernel 4: fused outer-product GEMM (128x128 tile, K=128) + epilogue GEMM.
// All LDS traffic in MFMA-fragment order (lane-linear, conflict-free).
// ---------------------------------------------------------------------------
__global__ __launch_bounds__(256) void main_kernel(
    const __hip_bfloat16* __restrict__ a_t, const __hip_bfloat16* __restrict__ b_t,
    const __hip_bfloat16* __restrict__ wo_f, const float* __restrict__ bo,
    const float* __restrict__ ninv, float* __restrict__ out)
{
    // Overlay: main loop A_f [0,8192) + B_f [8192,16384) shorts (frag order,
    // 16 frags x 512 each). Epilogue P: 32 frags x 516 shorts = [0,16512).
    __shared__ __align__(16) short lds[16512];

    const int t = threadIdx.x, l = t & 63, wv = t >> 6;
    const int q = l >> 4, c16 = l & 15;
    const int bi = blockIdx.x, bj = blockIdx.y;
    const int wr = wv >> 1, wc = wv & 1;
    const size_t Ibase = (size_t)bi * 128, Jbase = (size_t)bj * 128;

    float4v acc[4][4];
    #pragma unroll
    for (int ti = 0; ti < 4; ++ti)
        #pragma unroll
        for (int tj = 0; tj < 4; ++tj)
            acc[ti][tj] = (float4v){0.f, 0.f, 0.f, 0.f};

    // K = 128 in 2 stages of 64. Fragment id f: h=f>>3, ti=(f>>1)&3, kk=f&1.
    for (int st = 0; st < 2; ++st) {
        if (st) __syncthreads();
        #pragma unroll
        for (int i = 0; i < 4; ++i) {
            int f  = i * 4 + wv;
            int h  = f >> 3, ti = (f >> 1) & 3, kk = f & 1;
            int row  = h * 64 + ti * 16 + c16;
            int koff = st * 64 + kk * 32 + q * 8;
            *(short8*)&lds[f * 512 + l * 8] =
                *(const short8*)&a_t[(Ibase + row) * S_DIM + koff];
            *(short8*)&lds[8192 + f * 512 + l * 8] =
                *(const short8*)&b_t[(Jbase + row) * S_DIM + koff];
        }
        __syncthreads();
        #pragma unroll
        for (int kk = 0; kk < 2; ++kk) {
            short8 af[4], bf[4];
            #pragma unroll
            for (int ti = 0; ti < 4; ++ti)
                af[ti] = *(const short8*)&lds[((wr * 4 + ti) * 2 + kk) * 512 + l * 8];
            #pragma unroll
            for (int tj = 0; tj < 4; ++tj)
                bf[tj] = *(const short8*)&lds[8192 + ((wc * 4 + tj) * 2 + kk) * 512 + l * 8];
            #pragma unroll
            for (int ti = 0; ti < 4; ++ti)
                #pragma unroll
                for (int tj = 0; tj < 4; ++tj)
                    acc[ti][tj] = __builtin_amdgcn_mfma_f32_16x16x32_bf16(
                        af[ti], bf[tj], acc[ti][tj], 0, 0, 0);
        }
    }

    __syncthreads();
    // Scatter acc -> P fragments. Value (pair p, c=Il&31, d=Jl&31) lives at
    // frag d, offset (c>>3)*128 + p*8 + (c&7). rr gives 4 consecutive shorts.
    #pragma unroll
    for (int ti = 0; ti < 4; ++ti)
        #pragma unroll
        for (int tj = 0; tj < 4; ++tj) {
            int d  = ((tj & 1) * 16) + c16;                    // (tj*16+c16)&31
            int c0 = ((ti & 1) * 16) + q * 4;                  // (ti*16+q*4)&31
            int p  = (wr * 2 + (ti >> 1)) * 4 + wc * 2 + (tj >> 1);
            short4v pk;
            #pragma unroll
            for (int rr = 0; rr < 4; ++rr)
                pk[rr] = f2bf(acc[ti][tj][rr]);
            *(short4v*)&lds[d * 516 + (c0 >> 3) * 128 + p * 8 + (c0 & 7)] = pk;
        }
    __syncthreads();

    // Epilogue GEMM: P [16 pairs x 1024] @ wo_f -> [16 x 128].
    // Wave wv owns z-tiles 2wv, 2wv+1. All reads lane-linear.
    float4v oacc0 = {0.f, 0.f, 0.f, 0.f};
    float4v oacc1 = {0.f, 0.f, 0.f, 0.f};
    const __hip_bfloat16* wbase0 = wo_f + (size_t)(wv * 2    ) * 32 * 512;
    const __hip_bfloat16* wbase1 = wo_f + (size_t)(wv * 2 + 1) * 32 * 512;
    #pragma unroll 4
    for (int d = 0; d < 32; ++d) {
        union { short8 v8; short4v v4[2]; } pu;
        pu.v4[0] = *(const short4v*)&lds[d * 516 + l * 8];
        pu.v4[1] = *(const short4v*)&lds[d * 516 + l * 8 + 4];
        short8 wf0 = *(const short8*)&wbase0[(size_t)(d * 64 + l) * 8];
        short8 wf1 = *(const short8*)&wbase1[(size_t)(d * 64 + l) * 8];
        oacc0 = __builtin_amdgcn_mfma_f32_16x16x32_bf16(pu.v8, wf0, oacc0, 0, 0, 0);
        oacc1 = __builtin_amdgcn_mfma_f32_16x16x32_bf16(pu.v8, wf1, oacc1, 0, 0, 0);
    }

    // D: row = pair = q*4+rr -> (i_loc = q, j_loc = rr); col = z offset = c16
    const int gi = bi * 4 + q;
    float nvv[4];
    #pragma unroll
    for (int rr = 0; rr < 4; ++rr)
        nvv[rr] = ninv[gi * N_DIM + bj * 4 + rr];
    #pragma unroll
    for (int tile = 0; tile < 2; ++tile) {
        int z = wv * 32 + tile * 16 + c16;
        float bz = bo[z];
        float4v oacc = tile ? oacc1 : oacc0;
        #pragma unroll
        for (int rr = 0; rr < 4; ++rr) {
            int gj = bj * 4 + rr;
            out[((size_t)gi * N_DIM + gj) * CZ + z] = (oacc[rr] + bz) * nvv[rr];
        }
    }
}

extern "C" void kernel_launch(void* const* d_in, const int* in_sizes, int n_in,
                              void* d_out, int out_size, void* d_ws, size_t ws_size,
                              hipStream_t stream) {
    const float* m    = (const float*)d_in[0];
    const float* mask = (const float*)d_in[1];
    const float* lnw  = (const float*)d_in[2];
    const float* lnb  = (const float*)d_in[3];
    const float* w1   = (const float*)d_in[4];
    const float* b1   = (const float*)d_in[5];
    const float* w2   = (const float*)d_in[6];
    const float* b2   = (const float*)d_in[7];
    const float* wo   = (const float*)d_in[8];
    const float* bo   = (const float*)d_in[9];
    float* out = (float*)d_out;

    char* ws = (char*)d_ws;
    __hip_bfloat16* a_t  = (__hip_bfloat16*)ws;                          // 2 MB
    __hip_bfloat16* b_t  = (__hip_bfloat16*)(ws + (2u << 20));           // 2 MB
    __hip_bfloat16* wo_f = (__hip_bfloat16*)(ws + (4u << 20));           // 256 KB
    float*          ninv = (float*)(ws + (4u << 20) + (256u << 10));     // 256 KB

    prep_kernel<<<256, 256, 0, stream>>>(m, mask, lnw, lnb, w1, b1, w2, b2, a_t, b_t);
    norm_kernel<<<N_DIM, 256, 0, stream>>>(mask, ninv);
    wot_kernel<<<64, 256, 0, stream>>>(wo, wo_f);
    main_kernel<<<dim3(64, 64), 256, 0, stream>>>(a_t, b_t, wo_f, bo, ninv, out);
}

// Round 4
// 185.654 us; speedup vs baseline: 1.3466x; 1.0611x over previous
//
#include <hip/hip_runtime.h>
#include <hip/hip_bf16.h>

typedef __attribute__((ext_vector_type(8))) short short8;
typedef __attribute__((ext_vector_type(4))) short short4v;
typedef __attribute__((ext_vector_type(4))) float float4v;

#define S_DIM 128
#define N_DIM 256
#define CM    256
#define CH    32
#define CZ    128

static __device__ __forceinline__ short f2bf(float v) {
    return __builtin_bit_cast(short, __float2bfloat16(v));
}

// ---------------------------------------------------------------------------
// Fused aux kernel, 384 blocks x 256 thr:
//   blocks [0,256):   LayerNorm + dual projection -> a_t/b_t [N*CH][S] bf16.
//     Block owns 4 n x 32 s x all 64 cols -> coalesced 64 B/thread stores.
//   blocks [256,320): wo -> fragment-ordered wo_f.
//   blocks [320,384): ninv[i][j] = 1/(sum_s mask[s,i]mask[s,j] + 1e-3), 4 i each.
// ---------------------------------------------------------------------------
__global__ __launch_bounds__(256) void prep_aux_kernel(
    const float* __restrict__ m, const float* __restrict__ mask,
    const float* __restrict__ lnw, const float* __restrict__ lnb,
    const float* __restrict__ w1, const float* __restrict__ b1,
    const float* __restrict__ w2, const float* __restrict__ b2,
    const float* __restrict__ wo, const float* __restrict__ bo,
    __hip_bfloat16* __restrict__ a_t, __hip_bfloat16* __restrict__ b_t,
    __hip_bfloat16* __restrict__ wo_f, float* __restrict__ ninv)
{
    __shared__ __align__(16) char lds_raw[101376];
    __hip_bfloat16* ln_lds = (__hip_bfloat16*)lds_raw;             // 128 x 264
    __hip_bfloat16* w_lds  = (__hip_bfloat16*)(lds_raw + 67584);   // 64 x 264
    __hip_bfloat16* st_lds = (__hip_bfloat16*)lds_raw;             // 256 x 40 (overlay)

    const int bid = blockIdx.x, t = threadIdx.x;

    if (bid >= 320) {                       // ---- norm ----
        int i0 = (bid - 320) * 4, j = t;
        float a0 = 0.f, a1 = 0.f, a2 = 0.f, a3 = 0.f;
        for (int s = 0; s < S_DIM; ++s) {
            float mj = mask[s * N_DIM + j];
            a0 += mask[s * N_DIM + i0 + 0] * mj;
            a1 += mask[s * N_DIM + i0 + 1] * mj;
            a2 += mask[s * N_DIM + i0 + 2] * mj;
            a3 += mask[s * N_DIM + i0 + 3] * mj;
        }
        ninv[(i0 + 0) * N_DIM + j] = 1.0f / (a0 + 1e-3f);
        ninv[(i0 + 1) * N_DIM + j] = 1.0f / (a1 + 1e-3f);
        ninv[(i0 + 2) * N_DIM + j] = 1.0f / (a2 + 1e-3f);
        ninv[(i0 + 3) * N_DIM + j] = 1.0f / (a3 + 1e-3f);
        return;
    }
    if (bid >= 256) {                       // ---- wot ----
        int fidx = (bid - 256) * 256 + t;   // 16384 lane-slots
        int l  = fidx & 63;
        int d  = (fidx >> 6) & 31;
        int zt = fidx >> 11;
        int z  = zt * 16 + (l & 15);
        int cb = (l >> 4) * 8;
        short8 frag;
        #pragma unroll
        for (int j = 0; j < 8; ++j)
            frag[j] = f2bf(wo[(size_t)((cb + j) * 32 + d) * CZ + z]);
        *(short8*)&wo_f[(size_t)fidx * 8] = frag;
        return;
    }

    // ---- prep: 4 n x 32 s per block ----
    const int lane = t & 63, wv = t >> 6;
    const int q = lane >> 4, c16 = lane & 15;
    const int n0 = (bid & 63) * 4, s0 = (bid >> 6) * 32;

    // stage w transposed: w_t[c][k] = w{1,2}[k][c]
    #pragma unroll 4
    for (int i = 0; i < 64; ++i) {
        int e = i * 256 + t;
        int k = e >> 6, c = e & 63;
        float v = (c < CH) ? w1[k * CH + c] : w2[k * CH + (c - CH)];
        w_lds[c * 264 + k] = __float2bfloat16(v);
    }

    float4 lw = ((const float4*)lnw)[lane];
    float4 lb = ((const float4*)lnb)[lane];

    // LayerNorm: 32 rows per wave. rl = sl*4 + nl.
    #pragma unroll 2
    for (int it = 0; it < 32; ++it) {
        int rl = wv * 32 + it;
        int r  = (s0 + (rl >> 2)) * N_DIM + n0 + (rl & 3);
        float4 mv = ((const float4*)(m + (size_t)r * CM))[lane];
        float s1 = mv.x + mv.y + mv.z + mv.w;
        float s2 = mv.x*mv.x + mv.y*mv.y + mv.z*mv.z + mv.w*mv.w;
        #pragma unroll
        for (int o = 32; o > 0; o >>= 1) {
            s1 += __shfl_xor(s1, o, 64);
            s2 += __shfl_xor(s2, o, 64);
        }
        float mu  = s1 * (1.0f / 256.0f);
        float var = s2 * (1.0f / 256.0f) - mu * mu;
        float rs  = rsqrtf(var + 1e-5f);
        int base = rl * 264 + lane * 4;
        ln_lds[base + 0] = __float2bfloat16((mv.x - mu) * rs * lw.x + lb.x);
        ln_lds[base + 1] = __float2bfloat16((mv.y - mu) * rs * lw.y + lb.y);
        ln_lds[base + 2] = __float2bfloat16((mv.z - mu) * rs * lw.z + lb.z);
        ln_lds[base + 3] = __float2bfloat16((mv.w - mu) * rs * lw.w + lb.w);
    }
    __syncthreads();

    // MFMA: wave wv does rows [wv*32, wv*32+32) x 64 cols
    float4v acc[2][4];
    #pragma unroll
    for (int rt = 0; rt < 2; ++rt)
        #pragma unroll
        for (int ct = 0; ct < 4; ++ct)
            acc[rt][ct] = (float4v){0.f, 0.f, 0.f, 0.f};
    #pragma unroll
    for (int ks = 0; ks < 8; ++ks) {
        int k0 = ks * 32 + q * 8;
        short8 af0 = *(const short8*)&ln_lds[(wv * 32      + c16) * 264 + k0];
        short8 af1 = *(const short8*)&ln_lds[(wv * 32 + 16 + c16) * 264 + k0];
        #pragma unroll
        for (int ct = 0; ct < 4; ++ct) {
            short8 wb = *(const short8*)&w_lds[(ct * 16 + c16) * 264 + k0];
            acc[0][ct] = __builtin_amdgcn_mfma_f32_16x16x32_bf16(af0, wb, acc[0][ct], 0, 0, 0);
            acc[1][ct] = __builtin_amdgcn_mfma_f32_16x16x32_bf16(af1, wb, acc[1][ct], 0, 0, 0);
        }
    }
    __syncthreads();   // all ln/w reads done; overlay st_lds

    // scatter: C/D row = wv*32 + rt*16 + q*4 + rr -> sl = wv*8+rt*4+q, nl = rr
    #pragma unroll
    for (int rt = 0; rt < 2; ++rt) {
        int sl = wv * 8 + rt * 4 + q;
        #pragma unroll
        for (int ct = 0; ct < 4; ++ct) {
            int cc = ct * 16 + c16;
            float bias = (cc < CH) ? b1[cc] : b2[cc - CH];
            #pragma unroll
            for (int rr = 0; rr < 4; ++rr) {
                int r = (s0 + sl) * N_DIM + n0 + rr;
                float val = (acc[rt][ct][rr] + bias) * mask[r];
                st_lds[(rr * 64 + cc) * 40 + sl] = __float2bfloat16(val);
            }
        }
    }
    __syncthreads();

    // coalesced store: thread t owns column (nl = t>>6, cc = t&63), 32 s = 64 B
    {
        int nl = t >> 6, cc = t & 63;
        int colg = (n0 + nl) * CH + (cc < CH ? cc : cc - CH);
        __hip_bfloat16* dst = (cc < CH ? a_t : b_t) + (size_t)colg * S_DIM + s0;
        #pragma unroll
        for (int v = 0; v < 4; ++v)
            *(short8*)(dst + v * 8) = *(const short8*)&st_lds[t * 40 + v * 8];
    }
}

// ---------------------------------------------------------------------------
// Main kernel: fused outer-product GEMM (128x128 tile, K=128) + epilogue GEMM.
// All LDS traffic in MFMA-fragment order (lane-linear, conflict-free).
// ---------------------------------------------------------------------------
__global__ __launch_bounds__(256) void main_kernel(
    const __hip_bfloat16* __restrict__ a_t, const __hip_bfloat16* __restrict__ b_t,
    const __hip_bfloat16* __restrict__ wo_f, const float* __restrict__ bo,
    const float* __restrict__ ninv, float* __restrict__ out)
{
    __shared__ __align__(16) short lds[16512];

    const int t = threadIdx.x, l = t & 63, wv = t >> 6;
    const int q = l >> 4, c16 = l & 15;
    const int bi = blockIdx.x, bj = blockIdx.y;
    const int wr = wv >> 1, wc = wv & 1;
    const size_t Ibase = (size_t)bi * 128, Jbase = (size_t)bj * 128;

    float4v acc[4][4];
    #pragma unroll
    for (int ti = 0; ti < 4; ++ti)
        #pragma unroll
        for (int tj = 0; tj < 4; ++tj)
            acc[ti][tj] = (float4v){0.f, 0.f, 0.f, 0.f};

    for (int st = 0; st < 2; ++st) {
        if (st) __syncthreads();
        #pragma unroll
        for (int i = 0; i < 4; ++i) {
            int f  = i * 4 + wv;
            int h  = f >> 3, ti = (f >> 1) & 3, kk = f & 1;
            int row  = h * 64 + ti * 16 + c16;
            int koff = st * 64 + kk * 32 + q * 8;
            *(short8*)&lds[f * 512 + l * 8] =
                *(const short8*)&a_t[(Ibase + row) * S_DIM + koff];
            *(short8*)&lds[8192 + f * 512 + l * 8] =
                *(const short8*)&b_t[(Jbase + row) * S_DIM + koff];
        }
        __syncthreads();
        #pragma unroll
        for (int kk = 0; kk < 2; ++kk) {
            short8 af[4], bf[4];
            #pragma unroll
            for (int ti = 0; ti < 4; ++ti)
                af[ti] = *(const short8*)&lds[((wr * 4 + ti) * 2 + kk) * 512 + l * 8];
            #pragma unroll
            for (int tj = 0; tj < 4; ++tj)
                bf[tj] = *(const short8*)&lds[8192 + ((wc * 4 + tj) * 2 + kk) * 512 + l * 8];
            #pragma unroll
            for (int ti = 0; ti < 4; ++ti)
                #pragma unroll
                for (int tj = 0; tj < 4; ++tj)
                    acc[ti][tj] = __builtin_amdgcn_mfma_f32_16x16x32_bf16(
                        af[ti], bf[tj], acc[ti][tj], 0, 0, 0);
        }
    }

    __syncthreads();
    #pragma unroll
    for (int ti = 0; ti < 4; ++ti)
        #pragma unroll
        for (int tj = 0; tj < 4; ++tj) {
            int d  = ((tj & 1) * 16) + c16;
            int c0 = ((ti & 1) * 16) + q * 4;
            int p  = (wr * 2 + (ti >> 1)) * 4 + wc * 2 + (tj >> 1);
            short4v pk;
            #pragma unroll
            for (int rr = 0; rr < 4; ++rr)
                pk[rr] = f2bf(acc[ti][tj][rr]);
            *(short4v*)&lds[d * 516 + (c0 >> 3) * 128 + p * 8 + (c0 & 7)] = pk;
        }
    __syncthreads();

    float4v oacc0 = {0.f, 0.f, 0.f, 0.f};
    float4v oacc1 = {0.f, 0.f, 0.f, 0.f};
    const __hip_bfloat16* wbase0 = wo_f + (size_t)(wv * 2    ) * 32 * 512;
    const __hip_bfloat16* wbase1 = wo_f + (size_t)(wv * 2 + 1) * 32 * 512;
    #pragma unroll 4
    for (int d = 0; d < 32; ++d) {
        union { short8 v8; short4v v4[2]; } pu;
        pu.v4[0] = *(const short4v*)&lds[d * 516 + l * 8];
        pu.v4[1] = *(const short4v*)&lds[d * 516 + l * 8 + 4];
        short8 wf0 = *(const short8*)&wbase0[(size_t)(d * 64 + l) * 8];
        short8 wf1 = *(const short8*)&wbase1[(size_t)(d * 64 + l) * 8];
        oacc0 = __builtin_amdgcn_mfma_f32_16x16x32_bf16(pu.v8, wf0, oacc0, 0, 0, 0);
        oacc1 = __builtin_amdgcn_mfma_f32_16x16x32_bf16(pu.v8, wf1, oacc1, 0, 0, 0);
    }

    const int gi = bi * 4 + q;
    float nvv[4];
    #pragma unroll
    for (int rr = 0; rr < 4; ++rr)
        nvv[rr] = ninv[gi * N_DIM + bj * 4 + rr];
    #pragma unroll
    for (int tile = 0; tile < 2; ++tile) {
        int z = wv * 32 + tile * 16 + c16;
        float bz = bo[z];
        float4v oacc = tile ? oacc1 : oacc0;
        #pragma unroll
        for (int rr = 0; rr < 4; ++rr) {
            int gj = bj * 4 + rr;
            out[((size_t)gi * N_DIM + gj) * CZ + z] = (oacc[rr] + bz) * nvv[rr];
        }
    }
}

extern "C" void kernel_launch(void* const* d_in, const int* in_sizes, int n_in,
                              void* d_out, int out_size, void* d_ws, size_t ws_size,
                              hipStream_t stream) {
    const float* m    = (const float*)d_in[0];
    const float* mask = (const float*)d_in[1];
    const float* lnw  = (const float*)d_in[2];
    const float* lnb  = (const float*)d_in[3];
    const float* w1   = (const float*)d_in[4];
    const float* b1   = (const float*)d_in[5];
    const float* w2   = (const float*)d_in[6];
    const float* b2   = (const float*)d_in[7];
    const float* wo   = (const float*)d_in[8];
    const float* bo   = (const float*)d_in[9];
    float* out = (float*)d_out;

    char* ws = (char*)d_ws;
    __hip_bfloat16* a_t  = (__hip_bfloat16*)ws;                          // 2 MB
    __hip_bfloat16* b_t  = (__hip_bfloat16*)(ws + (2u << 20));           // 2 MB
    __hip_bfloat16* wo_f = (__hip_bfloat16*)(ws + (4u << 20));           // 256 KB
    float*          ninv = (float*)(ws + (4u << 20) + (256u << 10));     // 256 KB

    prep_aux_kernel<<<384, 256, 0, stream>>>(m, mask, lnw, lnb, w1, b1, w2, b2,
                                             wo, bo, a_t, b_t, wo_f, ninv);
    main_kernel<<<dim3(64, 64), 256, 0, stream>>>(a_t, b_t, wo_f, bo, ninv, out);
}

// Round 5
// 174.927 us; speedup vs baseline: 1.4292x; 1.0613x over previous
//
#include <hip/hip_runtime.h>
#include <hip/hip_bf16.h>

typedef __attribute__((ext_vector_type(8))) short short8;
typedef __attribute__((ext_vector_type(4))) short short4v;
typedef __attribute__((ext_vector_type(4))) float float4v;

#define S_DIM 128
#define N_DIM 256
#define CM    256
#define CH    32
#define CZ    128

static __device__ __forceinline__ short f2bf(float v) {
    return __builtin_bit_cast(short, __float2bfloat16(v));
}

// ---------------------------------------------------------------------------
// Fused aux kernel, 384 blocks x 256 thr (unchanged from R4):
//   blocks [0,256):   LayerNorm + dual projection -> a_t/b_t [N*CH][S] bf16.
//   blocks [256,320): wo -> fragment-ordered wo_f.
//   blocks [320,384): ninv[i][j] = 1/(sum_s mask[s,i]mask[s,j] + 1e-3).
// ---------------------------------------------------------------------------
__global__ __launch_bounds__(256) void prep_aux_kernel(
    const float* __restrict__ m, const float* __restrict__ mask,
    const float* __restrict__ lnw, const float* __restrict__ lnb,
    const float* __restrict__ w1, const float* __restrict__ b1,
    const float* __restrict__ w2, const float* __restrict__ b2,
    const float* __restrict__ wo, const float* __restrict__ bo,
    __hip_bfloat16* __restrict__ a_t, __hip_bfloat16* __restrict__ b_t,
    __hip_bfloat16* __restrict__ wo_f, float* __restrict__ ninv)
{
    __shared__ __align__(16) char lds_raw[101376];
    __hip_bfloat16* ln_lds = (__hip_bfloat16*)lds_raw;             // 128 x 264
    __hip_bfloat16* w_lds  = (__hip_bfloat16*)(lds_raw + 67584);   // 64 x 264
    __hip_bfloat16* st_lds = (__hip_bfloat16*)lds_raw;             // 256 x 40 (overlay)

    const int bid = blockIdx.x, t = threadIdx.x;

    if (bid >= 320) {                       // ---- norm ----
        int i0 = (bid - 320) * 4, j = t;
        float a0 = 0.f, a1 = 0.f, a2 = 0.f, a3 = 0.f;
        for (int s = 0; s < S_DIM; ++s) {
            float mj = mask[s * N_DIM + j];
            a0 += mask[s * N_DIM + i0 + 0] * mj;
            a1 += mask[s * N_DIM + i0 + 1] * mj;
            a2 += mask[s * N_DIM + i0 + 2] * mj;
            a3 += mask[s * N_DIM + i0 + 3] * mj;
        }
        ninv[(i0 + 0) * N_DIM + j] = 1.0f / (a0 + 1e-3f);
        ninv[(i0 + 1) * N_DIM + j] = 1.0f / (a1 + 1e-3f);
        ninv[(i0 + 2) * N_DIM + j] = 1.0f / (a2 + 1e-3f);
        ninv[(i0 + 3) * N_DIM + j] = 1.0f / (a3 + 1e-3f);
        return;
    }
    if (bid >= 256) {                       // ---- wot ----
        int fidx = (bid - 256) * 256 + t;
        int l  = fidx & 63;
        int d  = (fidx >> 6) & 31;
        int zt = fidx >> 11;
        int z  = zt * 16 + (l & 15);
        int cb = (l >> 4) * 8;
        short8 frag;
        #pragma unroll
        for (int j = 0; j < 8; ++j)
            frag[j] = f2bf(wo[(size_t)((cb + j) * 32 + d) * CZ + z]);
        *(short8*)&wo_f[(size_t)fidx * 8] = frag;
        return;
    }

    // ---- prep: 4 n x 32 s per block ----
    const int lane = t & 63, wv = t >> 6;
    const int q = lane >> 4, c16 = lane & 15;
    const int n0 = (bid & 63) * 4, s0 = (bid >> 6) * 32;

    #pragma unroll 4
    for (int i = 0; i < 64; ++i) {
        int e = i * 256 + t;
        int k = e >> 6, c = e & 63;
        float v = (c < CH) ? w1[k * CH + c] : w2[k * CH + (c - CH)];
        w_lds[c * 264 + k] = __float2bfloat16(v);
    }

    float4 lw = ((const float4*)lnw)[lane];
    float4 lb = ((const float4*)lnb)[lane];

    #pragma unroll 2
    for (int it = 0; it < 32; ++it) {
        int rl = wv * 32 + it;
        int r  = (s0 + (rl >> 2)) * N_DIM + n0 + (rl & 3);
        float4 mv = ((const float4*)(m + (size_t)r * CM))[lane];
        float s1 = mv.x + mv.y + mv.z + mv.w;
        float s2 = mv.x*mv.x + mv.y*mv.y + mv.z*mv.z + mv.w*mv.w;
        #pragma unroll
        for (int o = 32; o > 0; o >>= 1) {
            s1 += __shfl_xor(s1, o, 64);
            s2 += __shfl_xor(s2, o, 64);
        }
        float mu  = s1 * (1.0f / 256.0f);
        float var = s2 * (1.0f / 256.0f) - mu * mu;
        float rs  = rsqrtf(var + 1e-5f);
        int base = rl * 264 + lane * 4;
        ln_lds[base + 0] = __float2bfloat16((mv.x - mu) * rs * lw.x + lb.x);
        ln_lds[base + 1] = __float2bfloat16((mv.y - mu) * rs * lw.y + lb.y);
        ln_lds[base + 2] = __float2bfloat16((mv.z - mu) * rs * lw.z + lb.z);
        ln_lds[base + 3] = __float2bfloat16((mv.w - mu) * rs * lw.w + lb.w);
    }
    __syncthreads();

    float4v acc[2][4];
    #pragma unroll
    for (int rt = 0; rt < 2; ++rt)
        #pragma unroll
        for (int ct = 0; ct < 4; ++ct)
            acc[rt][ct] = (float4v){0.f, 0.f, 0.f, 0.f};
    #pragma unroll
    for (int ks = 0; ks < 8; ++ks) {
        int k0 = ks * 32 + q * 8;
        short8 af0 = *(const short8*)&ln_lds[(wv * 32      + c16) * 264 + k0];
        short8 af1 = *(const short8*)&ln_lds[(wv * 32 + 16 + c16) * 264 + k0];
        #pragma unroll
        for (int ct = 0; ct < 4; ++ct) {
            short8 wb = *(const short8*)&w_lds[(ct * 16 + c16) * 264 + k0];
            acc[0][ct] = __builtin_amdgcn_mfma_f32_16x16x32_bf16(af0, wb, acc[0][ct], 0, 0, 0);
            acc[1][ct] = __builtin_amdgcn_mfma_f32_16x16x32_bf16(af1, wb, acc[1][ct], 0, 0, 0);
        }
    }
    __syncthreads();

    #pragma unroll
    for (int rt = 0; rt < 2; ++rt) {
        int sl = wv * 8 + rt * 4 + q;
        #pragma unroll
        for (int ct = 0; ct < 4; ++ct) {
            int cc = ct * 16 + c16;
            float bias = (cc < CH) ? b1[cc] : b2[cc - CH];
            #pragma unroll
            for (int rr = 0; rr < 4; ++rr) {
                int r = (s0 + sl) * N_DIM + n0 + rr;
                float val = (acc[rt][ct][rr] + bias) * mask[r];
                st_lds[(rr * 64 + cc) * 40 + sl] = __float2bfloat16(val);
            }
        }
    }
    __syncthreads();

    {
        int nl = t >> 6, cc = t & 63;
        int colg = (n0 + nl) * CH + (cc < CH ? cc : cc - CH);
        __hip_bfloat16* dst = (cc < CH ? a_t : b_t) + (size_t)colg * S_DIM + s0;
        #pragma unroll
        for (int v = 0; v < 4; ++v)
            *(short8*)(dst + v * 8) = *(const short8*)&st_lds[t * 40 + v * 8];
    }
}

// ---------------------------------------------------------------------------
// Main kernel v2: 2 j-tiles per block. A fragments in registers (reused across
// both tiles); B staged per 64-K stage in LDS; P1/P2 fragment-ordered in LDS;
// one epilogue GEMM [32 pairs x 1024] @ wo_f reads wo_f ONCE per 2 tiles.
// LDS: B [0,8192) shorts; P2 overlays [0,16512); P1 [16512,33024). 64.5 KB.
// ---------------------------------------------------------------------------
__global__ __launch_bounds__(256, 2) void main_kernel(
    const __hip_bfloat16* __restrict__ a_t, const __hip_bfloat16* __restrict__ b_t,
    const __hip_bfloat16* __restrict__ wo_f, const float* __restrict__ bo,
    const float* __restrict__ ninv, float* __restrict__ out)
{
    __shared__ __align__(16) short lds[33024];

    const int t = threadIdx.x, l = t & 63, wv = t >> 6;
    const int q = l >> 4, c16 = l & 15;
    const int bi = blockIdx.x, bj0 = blockIdx.y * 2;
    const int wr = wv >> 1, wc = wv & 1;
    const size_t Ibase = (size_t)bi * 128;

    // A fragments -> registers, once. af[sk][ti], sk = st*2+kk (K quarter).
    short8 af[4][4];
    #pragma unroll
    for (int sk = 0; sk < 4; ++sk) {
        int koff = sk * 32 + q * 8;
        #pragma unroll
        for (int ti = 0; ti < 4; ++ti) {
            int row = wr * 64 + ti * 16 + c16;
            af[sk][ti] = *(const short8*)&a_t[(Ibase + row) * S_DIM + koff];
        }
    }

    #pragma unroll
    for (int tau = 0; tau < 2; ++tau) {
        const size_t Jbase = (size_t)(bj0 + tau) * 128;
        float4v acc[4][4];
        #pragma unroll
        for (int ti = 0; ti < 4; ++ti)
            #pragma unroll
            for (int tj = 0; tj < 4; ++tj)
                acc[ti][tj] = (float4v){0.f, 0.f, 0.f, 0.f};

        #pragma unroll
        for (int st = 0; st < 2; ++st) {
            // B stage st -> LDS [0,8192)
            #pragma unroll
            for (int i = 0; i < 4; ++i) {
                int f  = i * 4 + wv;
                int h  = f >> 3, ti = (f >> 1) & 3, kk = f & 1;
                int row  = h * 64 + ti * 16 + c16;
                int koff = st * 64 + kk * 32 + q * 8;
                *(short8*)&lds[f * 512 + l * 8] =
                    *(const short8*)&b_t[(Jbase + row) * S_DIM + koff];
            }
            __syncthreads();
            #pragma unroll
            for (int kk = 0; kk < 2; ++kk) {
                short8 bf[4];
                #pragma unroll
                for (int tj = 0; tj < 4; ++tj)
                    bf[tj] = *(const short8*)&lds[((wc * 4 + tj) * 2 + kk) * 512 + l * 8];
                #pragma unroll
                for (int ti = 0; ti < 4; ++ti)
                    #pragma unroll
                    for (int tj = 0; tj < 4; ++tj)
                        acc[ti][tj] = __builtin_amdgcn_mfma_f32_16x16x32_bf16(
                            af[st * 2 + kk][ti], bf[tj], acc[ti][tj], 0, 0, 0);
            }
            __syncthreads();   // all reads done before region reuse
        }

        // scatter acc -> P_tau (P1 at 16512, P2 at 0 overlaying B)
        const int pb = tau ? 0 : 16512;
        #pragma unroll
        for (int ti = 0; ti < 4; ++ti)
            #pragma unroll
            for (int tj = 0; tj < 4; ++tj) {
                int d  = ((tj & 1) * 16) + c16;
                int c0 = ((ti & 1) * 16) + q * 4;
                int p  = (wr * 2 + (ti >> 1)) * 4 + wc * 2 + (tj >> 1);
                short4v pk;
                #pragma unroll
                for (int rr = 0; rr < 4; ++rr)
                    pk[rr] = f2bf(acc[ti][tj][rr]);
                *(short4v*)&lds[pb + d * 516 + (c0 >> 3) * 128 + p * 8 + (c0 & 7)] = pk;
            }
    }
    __syncthreads();

    // Epilogue: [2 tiles x 16 pairs x 1024] @ wo_f -> 2 x [16 x 128].
    // Wave wv owns z-tiles 2wv, 2wv+1; wo_f read once for BOTH tiles.
    float4v oacc[2][2];
    #pragma unroll
    for (int a = 0; a < 2; ++a)
        #pragma unroll
        for (int b = 0; b < 2; ++b)
            oacc[a][b] = (float4v){0.f, 0.f, 0.f, 0.f};
    const __hip_bfloat16* wbase0 = wo_f + (size_t)(wv * 2    ) * 32 * 512;
    const __hip_bfloat16* wbase1 = wo_f + (size_t)(wv * 2 + 1) * 32 * 512;
    #pragma unroll 4
    for (int d = 0; d < 32; ++d) {
        union { short8 v8; short4v v4[2]; } p1, p2;
        p1.v4[0] = *(const short4v*)&lds[16512 + d * 516 + l * 8];
        p1.v4[1] = *(const short4v*)&lds[16512 + d * 516 + l * 8 + 4];
        p2.v4[0] = *(const short4v*)&lds[        d * 516 + l * 8];
        p2.v4[1] = *(const short4v*)&lds[        d * 516 + l * 8 + 4];
        short8 wf0 = *(const short8*)&wbase0[(size_t)(d * 64 + l) * 8];
        short8 wf1 = *(const short8*)&wbase1[(size_t)(d * 64 + l) * 8];
        oacc[0][0] = __builtin_amdgcn_mfma_f32_16x16x32_bf16(p1.v8, wf0, oacc[0][0], 0, 0, 0);
        oacc[0][1] = __builtin_amdgcn_mfma_f32_16x16x32_bf16(p1.v8, wf1, oacc[0][1], 0, 0, 0);
        oacc[1][0] = __builtin_amdgcn_mfma_f32_16x16x32_bf16(p2.v8, wf0, oacc[1][0], 0, 0, 0);
        oacc[1][1] = __builtin_amdgcn_mfma_f32_16x16x32_bf16(p2.v8, wf1, oacc[1][1], 0, 0, 0);
    }

    // D: row = pair = q*4+rr -> (i_loc = q, j_loc = rr); col = z offset = c16
    const int gi = bi * 4 + q;
    #pragma unroll
    for (int tau = 0; tau < 2; ++tau) {
        const int bj = bj0 + tau;
        float nvv[4];
        #pragma unroll
        for (int rr = 0; rr < 4; ++rr)
            nvv[rr] = ninv[gi * N_DIM + bj * 4 + rr];
        #pragma unroll
        for (int tile = 0; tile < 2; ++tile) {
            int z = wv * 32 + tile * 16 + c16;
            float bz = bo[z];
            float4v oa = oacc[tau][tile];
            #pragma unroll
            for (int rr = 0; rr < 4; ++rr) {
                int gj = bj * 4 + rr;
                out[((size_t)gi * N_DIM + gj) * CZ + z] = (oa[rr] + bz) * nvv[rr];
            }
        }
    }
}

extern "C" void kernel_launch(void* const* d_in, const int* in_sizes, int n_in,
                              void* d_out, int out_size, void* d_ws, size_t ws_size,
                              hipStream_t stream) {
    const float* m    = (const float*)d_in[0];
    const float* mask = (const float*)d_in[1];
    const float* lnw  = (const float*)d_in[2];
    const float* lnb  = (const float*)d_in[3];
    const float* w1   = (const float*)d_in[4];
    const float* b1   = (const float*)d_in[5];
    const float* w2   = (const float*)d_in[6];
    const float* b2   = (const float*)d_in[7];
    const float* wo   = (const float*)d_in[8];
    const float* bo   = (const float*)d_in[9];
    float* out = (float*)d_out;

    char* ws = (char*)d_ws;
    __hip_bfloat16* a_t  = (__hip_bfloat16*)ws;                          // 2 MB
    __hip_bfloat16* b_t  = (__hip_bfloat16*)(ws + (2u << 20));           // 2 MB
    __hip_bfloat16* wo_f = (__hip_bfloat16*)(ws + (4u << 20));           // 256 KB
    float*          ninv = (float*)(ws + (4u << 20) + (256u << 10));     // 256 KB

    prep_aux_kernel<<<384, 256, 0, stream>>>(m, mask, lnw, lnb, w1, b1, w2, b2,
                                             wo, bo, a_t, b_t, wo_f, ninv);
    main_kernel<<<dim3(64, 32), 256, 0, stream>>>(a_t, b_t, wo_f, bo, ninv, out);
}